// Round 10
// baseline (263.090 us; speedup 1.0000x reference)
//
#include <hip/hip_runtime.h>

#define H_ 768
#define W_ 1024
#define HW_ (H_ * W_)
#define NFRAMES 16
#define NPAIRS 15
#define NB_ 96                      // bands per pair, 8 rows each
#define BAND_ROWS 8
#define BAND_PX (BAND_ROWS * W_)    // 8192
#define ROWS_PER_BLK 4
#define BLKS_PER_PAIR (H_ / ROWS_PER_BLK)   // 192
#define MAXSEG BLKS_PER_PAIR        // worst case: every row-block feeds a band
#define NBANDS_ALL (NPAIRS * NB_)   // 1440

struct Xform {
    float R[9];
    float t[3];
};

// Projection happens in exactly ONE kernel (fill), so no cross-kernel
// bit-determinism is needed. Entry = (zq19 << 13) | slot13 where
// zq = (float_bits(z) + 0x1000) >> 13 (round-to-nearest, monotone in z),
// slot = ((vi&7)<<10) | ui. Positive-float bits >> 13 always fit 19 bits.
__device__ __forceinline__ bool project_px(
    float d, int u, int v,
    float fx, float fy, float cx, float cy,
    const Xform& XA, const Xform& XB,
    int& vi, int& ui, unsigned& zbits)
{
    if (d == 0.f) return false;                       // validA
    float x = ((float)u - cx) * d / fx;
    float y = ((float)v - cy) * d / fy;
    float pwx = __fmaf_rn(XA.R[0], x, __fmaf_rn(XA.R[1], y, __fmaf_rn(XA.R[2], d, XA.t[0])));
    float pwy = __fmaf_rn(XA.R[3], x, __fmaf_rn(XA.R[4], y, __fmaf_rn(XA.R[5], d, XA.t[1])));
    float pwz = __fmaf_rn(XA.R[6], x, __fmaf_rn(XA.R[7], y, __fmaf_rn(XA.R[8], d, XA.t[2])));
    float mx = pwx - XB.t[0];
    float my = pwy - XB.t[1];
    float mz = pwz - XB.t[2];
    float q0 = __fmaf_rn(XB.R[0], mx, __fmaf_rn(XB.R[3], my, XB.R[6] * mz));
    float q1 = __fmaf_rn(XB.R[1], mx, __fmaf_rn(XB.R[4], my, XB.R[7] * mz));
    float z  = __fmaf_rn(XB.R[2], mx, __fmaf_rn(XB.R[5], my, XB.R[8] * mz));
    if (!(z > 0.f)) return false;
    float u2 = fx * q0 / z + cx;
    float v2 = fy * q1 / z + cy;
    int uii = (int)rintf(u2);                         // round-half-even = jnp.round
    int vii = (int)rintf(v2);
    if (uii < 0 || uii >= W_ || vii < 0 || vii >= H_) return false;
    vi = vii; ui = uii; zbits = __float_as_uint(z);
    return true;
}

__global__ void prep_kernel(const float* __restrict__ pose,
                            Xform* __restrict__ xf,
                            unsigned* __restrict__ seg_cnt,
                            unsigned* __restrict__ alloc) {
    int t = threadIdx.x;
    if (t < NFRAMES) {
        const float* p = pose + t * 7;
        float tx = p[0], ty = p[1], tz = p[2];
        float x = p[3], y = p[4], z = p[5], w = p[6];
        float n = sqrtf(x * x + y * y + z * z + w * w);
        x /= n; y /= n; z /= n; w /= n;
        Xform X;
        X.R[0] = 1.f - 2.f * (y * y + z * z);
        X.R[1] = 2.f * (x * y - z * w);
        X.R[2] = 2.f * (x * z + y * w);
        X.R[3] = 2.f * (x * y + z * w);
        X.R[4] = 1.f - 2.f * (x * x + z * z);
        X.R[5] = 2.f * (y * z - x * w);
        X.R[6] = 2.f * (x * z - y * w);
        X.R[7] = 2.f * (y * z + x * w);
        X.R[8] = 1.f - 2.f * (x * x + y * y);
        X.t[0] = tx; X.t[1] = ty; X.t[2] = tz;
        xf[t] = X;
    }
    for (int i = t; i < NBANDS_ALL; i += 256) seg_cnt[i] = 0u;
    if (t == 0) alloc[0] = 0u;
}

__global__ void reset_alloc_kernel(unsigned* __restrict__ alloc) {
    alloc[0] = 0u;
}

// Single projection pass: bin entries (zq|slot) into per-band chunks
// reserved from a global bump allocator; record segment descriptors.
// Run-length slot allocation: a thread's consecutive pixels landing in the
// same band are allocated with ONE LDS atomicAdd (expected run ~5 px), so
// LDS same-address atomic serialization drops ~5x vs per-pixel atomics.
__global__ void fill_kernel(const float* __restrict__ pred,
                            const Xform* __restrict__ xf,
                            const float* __restrict__ Km,
                            unsigned* __restrict__ alloc,
                            unsigned* __restrict__ seg_cnt,
                            uint2* __restrict__ seg,
                            unsigned* __restrict__ bins, int pair0) {
    int pair = pair0 + blockIdx.x / BLKS_PER_PAIR;
    int rowblk = blockIdx.x % BLKS_PER_PAIR;
    int t = threadIdx.x;
    __shared__ unsigned cnt[NB_];
    __shared__ unsigned basev[NB_];
    __shared__ unsigned chunk_base;
    if (t < NB_) cnt[t] = 0u;
    __syncthreads();

    float fx = Km[0], cx = Km[2], fy = Km[4], cy = Km[5];
    Xform XA = xf[pair], XB = xf[pair + 1];
    int row = rowblk * ROWS_PER_BLK + (t >> 6);
    int px0 = (t & 63) * 16;
    const float* src = pred + (size_t)pair * HW_ + row * W_ + px0;

    unsigned entry[16];
    unsigned pk[16];
    // pass 1: project, pk[idx] = band (<96) or invalid sentinel
#pragma unroll
    for (int k = 0; k < 4; ++k) {
        float4 d4 = *(const float4*)(src + 4 * k);
        float dd[4] = {d4.x, d4.y, d4.z, d4.w};
#pragma unroll
        for (int j = 0; j < 4; ++j) {
            int idx = 4 * k + j;
            pk[idx] = 0xFFFFFFFFu;
            int vi, ui; unsigned zbits;
            if (project_px(dd[j], px0 + idx, row, fx, fy, cx, cy, XA, XB, vi, ui, zbits)) {
                unsigned slot = (((unsigned)vi & 7u) << 10) | (unsigned)ui;
                unsigned zq = (zbits + 0x1000u) >> 13;          // 19-bit monotone key
                entry[idx] = (zq << 13) | slot;
                pk[idx] = (unsigned)(vi >> 3);                  // band
            }
        }
    }
    // pass 2: run-length slot allocation (one atomic per run)
    {
        int i = 0;
        while (i < 16) {
            unsigned b = pk[i];
            if (b == 0xFFFFFFFFu) { ++i; continue; }
            int j = i + 1;
            while (j < 16 && pk[j] == b) ++j;
            unsigned base = atomicAdd(&cnt[b], (unsigned)(j - i));
            for (int k = i; k < j; ++k) pk[k] = (b << 16) | (base + (unsigned)(k - i));
            i = j;
        }
    }
    __syncthreads();
    if (t == 0) {
        unsigned run = 0;
        for (int i = 0; i < NB_; ++i) { unsigned c = cnt[i]; basev[i] = run; run += c; }
        chunk_base = atomicAdd(alloc, run);
    }
    __syncthreads();
    if (t < NB_ && cnt[t]) {
        unsigned b0 = chunk_base + basev[t];
        basev[t] = b0;                                          // absolute
        unsigned gb = (unsigned)(pair * NB_ + t);
        unsigned si = atomicAdd(&seg_cnt[gb], 1u);
        seg[(size_t)gb * MAXSEG + si] = make_uint2(b0, cnt[t]);
    }
    __syncthreads();
#pragma unroll
    for (int idx = 0; idx < 16; ++idx) {
        unsigned p = pk[idx];
        if (p != 0xFFFFFFFFu)
            bins[basev[p >> 16] + (p & 0xFFFFu)] = entry[idx];
    }
}

// Per-band LDS z-buffer from self-describing entries + fused masked reduce.
__global__ void zmin_kernel(const float* __restrict__ pred,
                            const unsigned* __restrict__ seg_cnt,
                            const uint2* __restrict__ seg,
                            const unsigned* __restrict__ bins,
                            float* __restrict__ partial_s,
                            unsigned* __restrict__ partial_c, int pair0) {
    int gband = pair0 * NB_ + blockIdx.x;
    int pair = gband / NB_;
    int band = gband % NB_;
    int t = threadIdx.x;
    __shared__ unsigned zb[BAND_PX];
#pragma unroll
    for (int k = 0; k < BAND_PX / 256; ++k) zb[k * 256 + t] = 0xFFFFFFFFu;
    __syncthreads();

    unsigned ns = seg_cnt[gband];
    const uint2* sgs = seg + (size_t)gband * MAXSEG;
    for (unsigned j = 0; j < ns; ++j) {
        uint2 sg = sgs[j];
        for (unsigned i = sg.x + t; i < sg.x + sg.y; i += 256) {
            unsigned e = bins[i];
            atomicMin(&zb[e & 8191u], e >> 13);
        }
    }
    __syncthreads();

    const float4* pb4 = (const float4*)(pred + (size_t)(pair + 1) * HW_ + (size_t)band * BAND_PX);
    const uint4* zb4 = (const uint4*)zb;
    float s = 0.f; unsigned c = 0u;
#pragma unroll
    for (int k = 0; k < BAND_PX / 1024; ++k) {
        int i4 = k * 256 + t;
        uint4 b = zb4[i4];
        float4 db = pb4[i4];
        if (b.x != 0xFFFFFFFFu) { s += __uint_as_float(b.x << 13) - db.x; ++c; } else if (db.x != 0.f) ++c;
        if (b.y != 0xFFFFFFFFu) { s += __uint_as_float(b.y << 13) - db.y; ++c; } else if (db.y != 0.f) ++c;
        if (b.z != 0xFFFFFFFFu) { s += __uint_as_float(b.z << 13) - db.z; ++c; } else if (db.z != 0.f) ++c;
        if (b.w != 0xFFFFFFFFu) { s += __uint_as_float(b.w << 13) - db.w; ++c; } else if (db.w != 0.f) ++c;
    }
    for (int off = 32; off > 0; off >>= 1) {
        s += __shfl_down(s, off);
        c += __shfl_down(c, off);
    }
    __shared__ float ls[4];
    __shared__ unsigned lc[4];
    int lane = t & 63, wid = t >> 6;
    if (lane == 0) { ls[wid] = s; lc[wid] = c; }
    __syncthreads();
    if (t == 0) {
        partial_s[gband] = ls[0] + ls[1] + ls[2] + ls[3];
        partial_c[gband] = lc[0] + lc[1] + lc[2] + lc[3];
    }
}

__global__ void final_kernel(const float* __restrict__ partial_s,
                             const unsigned* __restrict__ partial_c,
                             float* __restrict__ out) {
    int t = threadIdx.x;
    __shared__ float ps[NPAIRS];
    __shared__ unsigned pc[NPAIRS];
    int pair = t >> 4, sub = t & 15;
    float s = 0.f; unsigned c = 0u;
    if (t < NPAIRS * 16) {
#pragma unroll
        for (int j = 0; j < 6; ++j) {
            int g = pair * NB_ + sub + j * 16;
            s += partial_s[g];
            c += partial_c[g];
        }
        for (int m = 1; m < 16; m <<= 1) { s += __shfl_xor(s, m); c += __shfl_xor(c, m); }
        if (sub == 0) { ps[pair] = s; pc[pair] = c; }
    }
    __syncthreads();
    if (t == 0) {
        float acc = 0.f;
        for (int p = 0; p < NPAIRS; ++p) {
            unsigned cc = pc[p];
            if (cc < 1u) cc = 1u;
            acc += ps[p] / (float)cc;
        }
        out[0] = acc;
    }
}

extern "C" void kernel_launch(void* const* d_in, const int* in_sizes, int n_in,
                              void* d_out, int out_size, void* d_ws, size_t ws_size,
                              hipStream_t stream) {
    const float* pred = (const float*)d_in[0];   // (16,1,768,1024) f32
    const float* pose = (const float*)d_in[1];   // (16,7) f32
    const float* Km   = (const float*)d_in[2];   // (3,3) f32
    float* out = (float*)d_out;
    char* ws = (char*)d_ws;

    // ws layout (bytes):
    //     0: seg_cnt[1440]            (5760)
    //  5760: alloc[1]                 (4)
    //  5764: partial_c[1440]          (5760)
    // 11524: partial_s[1440]          (5760)  -> ends 17284
    // 17296: xf[16]                   (768)   -> ends 18064 (16-aligned)
    // 18064: seg[1440*192] uint2      (2211840) -> ends 2229904
    // 2229904: bins                   (pathA: 15*HW*4 ; pathB: HW*4)
    unsigned* seg_cnt   = (unsigned*)ws;
    unsigned* alloc     = (unsigned*)(ws + 5760);
    unsigned* partial_c = (unsigned*)(ws + 5764);
    float*    partial_s = (float*)(ws + 11524);
    Xform*    xf        = (Xform*)(ws + 17296);
    uint2*    seg       = (uint2*)(ws + 18064);
    unsigned* bins      = (unsigned*)(ws + 2229904);

    size_t needA = 2229904 + (size_t)NPAIRS * HW_ * sizeof(unsigned);
    bool pathA = ws_size >= needA;

    prep_kernel<<<1, 256, 0, stream>>>(pose, xf, seg_cnt, alloc);

    if (pathA) {
        fill_kernel<<<NPAIRS * BLKS_PER_PAIR, 256, 0, stream>>>(pred, xf, Km, alloc,
                                                                seg_cnt, seg, bins, 0);
        zmin_kernel<<<NPAIRS * NB_, 256, 0, stream>>>(pred, seg_cnt, seg, bins,
                                                      partial_s, partial_c, 0);
    } else {
        for (int p = 0; p < NPAIRS; ++p) {
            reset_alloc_kernel<<<1, 1, 0, stream>>>(alloc);
            fill_kernel<<<BLKS_PER_PAIR, 256, 0, stream>>>(pred, xf, Km, alloc,
                                                           seg_cnt, seg, bins, p);
            zmin_kernel<<<NB_, 256, 0, stream>>>(pred, seg_cnt, seg, bins,
                                                 partial_s, partial_c, p);
        }
    }

    final_kernel<<<1, 256, 0, stream>>>(partial_s, partial_c, out);
}

// Round 11
// 249.224 us; speedup vs baseline: 1.0556x; 1.0556x over previous
//
#include <hip/hip_runtime.h>

#define H_ 768
#define W_ 1024
#define HW_ (H_ * W_)
#define NFRAMES 16
#define NPAIRS 15
#define NB_ 96                      // bands per pair, 8 rows each
#define BAND_ROWS 8
#define BAND_PX (BAND_ROWS * W_)    // 8192
#define ROWS_PER_BLK 4
#define BLKS_PER_PAIR (H_ / ROWS_PER_BLK)   // 192
#define MAXSEG BLKS_PER_PAIR        // worst case: every row-block feeds a band
#define NBANDS_ALL (NPAIRS * NB_)   // 1440

struct Xform {
    float R[9];
    float t[3];
};

// Projection happens in exactly ONE kernel (fill), so no cross-kernel
// bit-determinism is needed. Entry = (zq19 << 13) | slot13 where
// zq = (float_bits(z) + 0x1000) >> 13 (round-to-nearest, monotone in z),
// slot = ((vi&7)<<10) | ui. Positive-float bits >> 13 always fit 19 bits.
__device__ __forceinline__ bool project_px(
    float d, int u, int v,
    float fx, float fy, float cx, float cy,
    const Xform& XA, const Xform& XB,
    int& vi, int& ui, unsigned& zbits)
{
    if (d == 0.f) return false;                       // validA
    float x = ((float)u - cx) * d / fx;
    float y = ((float)v - cy) * d / fy;
    float pwx = __fmaf_rn(XA.R[0], x, __fmaf_rn(XA.R[1], y, __fmaf_rn(XA.R[2], d, XA.t[0])));
    float pwy = __fmaf_rn(XA.R[3], x, __fmaf_rn(XA.R[4], y, __fmaf_rn(XA.R[5], d, XA.t[1])));
    float pwz = __fmaf_rn(XA.R[6], x, __fmaf_rn(XA.R[7], y, __fmaf_rn(XA.R[8], d, XA.t[2])));
    float mx = pwx - XB.t[0];
    float my = pwy - XB.t[1];
    float mz = pwz - XB.t[2];
    float q0 = __fmaf_rn(XB.R[0], mx, __fmaf_rn(XB.R[3], my, XB.R[6] * mz));
    float q1 = __fmaf_rn(XB.R[1], mx, __fmaf_rn(XB.R[4], my, XB.R[7] * mz));
    float z  = __fmaf_rn(XB.R[2], mx, __fmaf_rn(XB.R[5], my, XB.R[8] * mz));
    if (!(z > 0.f)) return false;
    float u2 = fx * q0 / z + cx;
    float v2 = fy * q1 / z + cy;
    int uii = (int)rintf(u2);                         // round-half-even = jnp.round
    int vii = (int)rintf(v2);
    if (uii < 0 || uii >= W_ || vii < 0 || vii >= H_) return false;
    vi = vii; ui = uii; zbits = __float_as_uint(z);
    return true;
}

__global__ void prep_kernel(const float* __restrict__ pose,
                            Xform* __restrict__ xf,
                            unsigned* __restrict__ seg_cnt,
                            unsigned* __restrict__ alloc) {
    int t = threadIdx.x;
    if (t < NFRAMES) {
        const float* p = pose + t * 7;
        float tx = p[0], ty = p[1], tz = p[2];
        float x = p[3], y = p[4], z = p[5], w = p[6];
        float n = sqrtf(x * x + y * y + z * z + w * w);
        x /= n; y /= n; z /= n; w /= n;
        Xform X;
        X.R[0] = 1.f - 2.f * (y * y + z * z);
        X.R[1] = 2.f * (x * y - z * w);
        X.R[2] = 2.f * (x * z + y * w);
        X.R[3] = 2.f * (x * y + z * w);
        X.R[4] = 1.f - 2.f * (x * x + z * z);
        X.R[5] = 2.f * (y * z - x * w);
        X.R[6] = 2.f * (x * z - y * w);
        X.R[7] = 2.f * (y * z + x * w);
        X.R[8] = 1.f - 2.f * (x * x + y * y);
        X.t[0] = tx; X.t[1] = ty; X.t[2] = tz;
        xf[t] = X;
    }
    for (int i = t; i < NBANDS_ALL; i += 256) seg_cnt[i] = 0u;
    if (t == 0) alloc[0] = 0u;
}

__global__ void reset_alloc_kernel(unsigned* __restrict__ alloc) {
    alloc[0] = 0u;
}

// Single projection pass: bin entries (zq|slot) into per-band chunks
// reserved from a global bump allocator; record segment descriptors.
// Wave-aggregated slot allocation: per pixel slot, ballot lanes by band and
// issue ONE LDS atomicAdd per distinct band in the wave (typically 1-2),
// with lane offsets from mask popcounts. All arrays statically indexed
// (rule #20: runtime-indexed arrays spill to scratch -- round-10 regression).
__global__ void fill_kernel(const float* __restrict__ pred,
                            const Xform* __restrict__ xf,
                            const float* __restrict__ Km,
                            unsigned* __restrict__ alloc,
                            unsigned* __restrict__ seg_cnt,
                            uint2* __restrict__ seg,
                            unsigned* __restrict__ bins, int pair0) {
    int pair = pair0 + blockIdx.x / BLKS_PER_PAIR;
    int rowblk = blockIdx.x % BLKS_PER_PAIR;
    int t = threadIdx.x;
    int lane = t & 63;
    __shared__ unsigned cnt[NB_];
    __shared__ unsigned basev[NB_];
    __shared__ unsigned chunk_base;
    if (t < NB_) cnt[t] = 0u;
    __syncthreads();

    float fx = Km[0], cx = Km[2], fy = Km[4], cy = Km[5];
    Xform XA = xf[pair], XB = xf[pair + 1];
    int row = rowblk * ROWS_PER_BLK + (t >> 6);
    int px0 = (t & 63) * 16;
    const float* src = pred + (size_t)pair * HW_ + row * W_ + px0;

    unsigned entry[16];
    unsigned pk[16];
    unsigned long long lt_mask = (1ULL << lane) - 1ULL;

#pragma unroll
    for (int k = 0; k < 4; ++k) {
        float4 d4 = *(const float4*)(src + 4 * k);
        float dd[4] = {d4.x, d4.y, d4.z, d4.w};
#pragma unroll
        for (int j = 0; j < 4; ++j) {
            int idx = 4 * k + j;
            // 1. project
            unsigned band = 0xFFFFFFFFu;
            int vi, ui; unsigned zbits;
            if (project_px(dd[j], px0 + idx, row, fx, fy, cx, cy, XA, XB, vi, ui, zbits)) {
                unsigned slot = (((unsigned)vi & 7u) << 10) | (unsigned)ui;
                unsigned zq = (zbits + 0x1000u) >> 13;          // 19-bit monotone key
                entry[idx] = (zq << 13) | slot;
                band = (unsigned)(vi >> 3);
            }
            // 2. wave-aggregated allocation (one atomic per distinct band)
            unsigned myloc = 0;
            unsigned long long V = __ballot(band != 0xFFFFFFFFu);
            while (V) {
                int srcl = __ffsll((unsigned long long)V) - 1;
                unsigned b = __shfl(band, srcl);
                unsigned long long m = __ballot(band == b) & V;
                unsigned base = 0;
                if (lane == srcl) base = atomicAdd(&cnt[b], (unsigned)__popcll(m));
                base = __shfl(base, srcl);
                if (band == b) myloc = base + (unsigned)__popcll(m & lt_mask);
                V &= ~m;
            }
            pk[idx] = (band != 0xFFFFFFFFu) ? ((band << 16) | myloc) : 0xFFFFFFFFu;
        }
    }
    __syncthreads();
    if (t == 0) {
        unsigned run = 0;
        for (int i = 0; i < NB_; ++i) { unsigned c = cnt[i]; basev[i] = run; run += c; }
        chunk_base = atomicAdd(alloc, run);
    }
    __syncthreads();
    if (t < NB_ && cnt[t]) {
        unsigned b0 = chunk_base + basev[t];
        basev[t] = b0;                                          // absolute
        unsigned gb = (unsigned)(pair * NB_ + t);
        unsigned si = atomicAdd(&seg_cnt[gb], 1u);
        seg[(size_t)gb * MAXSEG + si] = make_uint2(b0, cnt[t]);
    }
    __syncthreads();
#pragma unroll
    for (int idx = 0; idx < 16; ++idx) {
        unsigned p = pk[idx];
        if (p != 0xFFFFFFFFu)
            bins[basev[p >> 16] + (p & 0xFFFFu)] = entry[idx];
    }
}

// Per-band LDS z-buffer from self-describing entries + fused masked reduce.
__global__ void zmin_kernel(const float* __restrict__ pred,
                            const unsigned* __restrict__ seg_cnt,
                            const uint2* __restrict__ seg,
                            const unsigned* __restrict__ bins,
                            float* __restrict__ partial_s,
                            unsigned* __restrict__ partial_c, int pair0) {
    int gband = pair0 * NB_ + blockIdx.x;
    int pair = gband / NB_;
    int band = gband % NB_;
    int t = threadIdx.x;
    __shared__ unsigned zb[BAND_PX];
#pragma unroll
    for (int k = 0; k < BAND_PX / 256; ++k) zb[k * 256 + t] = 0xFFFFFFFFu;
    __syncthreads();

    unsigned ns = seg_cnt[gband];
    const uint2* sgs = seg + (size_t)gband * MAXSEG;
    for (unsigned j = 0; j < ns; ++j) {
        uint2 sg = sgs[j];
        for (unsigned i = sg.x + t; i < sg.x + sg.y; i += 256) {
            unsigned e = bins[i];
            atomicMin(&zb[e & 8191u], e >> 13);
        }
    }
    __syncthreads();

    const float4* pb4 = (const float4*)(pred + (size_t)(pair + 1) * HW_ + (size_t)band * BAND_PX);
    const uint4* zb4 = (const uint4*)zb;
    float s = 0.f; unsigned c = 0u;
#pragma unroll
    for (int k = 0; k < BAND_PX / 1024; ++k) {
        int i4 = k * 256 + t;
        uint4 b = zb4[i4];
        float4 db = pb4[i4];
        if (b.x != 0xFFFFFFFFu) { s += __uint_as_float(b.x << 13) - db.x; ++c; } else if (db.x != 0.f) ++c;
        if (b.y != 0xFFFFFFFFu) { s += __uint_as_float(b.y << 13) - db.y; ++c; } else if (db.y != 0.f) ++c;
        if (b.z != 0xFFFFFFFFu) { s += __uint_as_float(b.z << 13) - db.z; ++c; } else if (db.z != 0.f) ++c;
        if (b.w != 0xFFFFFFFFu) { s += __uint_as_float(b.w << 13) - db.w; ++c; } else if (db.w != 0.f) ++c;
    }
    for (int off = 32; off > 0; off >>= 1) {
        s += __shfl_down(s, off);
        c += __shfl_down(c, off);
    }
    __shared__ float ls[4];
    __shared__ unsigned lc[4];
    int lane = t & 63, wid = t >> 6;
    if (lane == 0) { ls[wid] = s; lc[wid] = c; }
    __syncthreads();
    if (t == 0) {
        partial_s[gband] = ls[0] + ls[1] + ls[2] + ls[3];
        partial_c[gband] = lc[0] + lc[1] + lc[2] + lc[3];
    }
}

__global__ void final_kernel(const float* __restrict__ partial_s,
                             const unsigned* __restrict__ partial_c,
                             float* __restrict__ out) {
    int t = threadIdx.x;
    __shared__ float ps[NPAIRS];
    __shared__ unsigned pc[NPAIRS];
    int pair = t >> 4, sub = t & 15;
    float s = 0.f; unsigned c = 0u;
    if (t < NPAIRS * 16) {
#pragma unroll
        for (int j = 0; j < 6; ++j) {
            int g = pair * NB_ + sub + j * 16;
            s += partial_s[g];
            c += partial_c[g];
        }
        for (int m = 1; m < 16; m <<= 1) { s += __shfl_xor(s, m); c += __shfl_xor(c, m); }
        if (sub == 0) { ps[pair] = s; pc[pair] = c; }
    }
    __syncthreads();
    if (t == 0) {
        float acc = 0.f;
        for (int p = 0; p < NPAIRS; ++p) {
            unsigned cc = pc[p];
            if (cc < 1u) cc = 1u;
            acc += ps[p] / (float)cc;
        }
        out[0] = acc;
    }
}

extern "C" void kernel_launch(void* const* d_in, const int* in_sizes, int n_in,
                              void* d_out, int out_size, void* d_ws, size_t ws_size,
                              hipStream_t stream) {
    const float* pred = (const float*)d_in[0];   // (16,1,768,1024) f32
    const float* pose = (const float*)d_in[1];   // (16,7) f32
    const float* Km   = (const float*)d_in[2];   // (3,3) f32
    float* out = (float*)d_out;
    char* ws = (char*)d_ws;

    // ws layout (bytes):
    //     0: seg_cnt[1440]            (5760)
    //  5760: alloc[1]                 (4)
    //  5764: partial_c[1440]          (5760)
    // 11524: partial_s[1440]          (5760)  -> ends 17284
    // 17296: xf[16]                   (768)   -> ends 18064 (16-aligned)
    // 18064: seg[1440*192] uint2      (2211840) -> ends 2229904
    // 2229904: bins                   (pathA: 15*HW*4 ; pathB: HW*4)
    unsigned* seg_cnt   = (unsigned*)ws;
    unsigned* alloc     = (unsigned*)(ws + 5760);
    unsigned* partial_c = (unsigned*)(ws + 5764);
    float*    partial_s = (float*)(ws + 11524);
    Xform*    xf        = (Xform*)(ws + 17296);
    uint2*    seg       = (uint2*)(ws + 18064);
    unsigned* bins      = (unsigned*)(ws + 2229904);

    size_t needA = 2229904 + (size_t)NPAIRS * HW_ * sizeof(unsigned);
    bool pathA = ws_size >= needA;

    prep_kernel<<<1, 256, 0, stream>>>(pose, xf, seg_cnt, alloc);

    if (pathA) {
        fill_kernel<<<NPAIRS * BLKS_PER_PAIR, 256, 0, stream>>>(pred, xf, Km, alloc,
                                                                seg_cnt, seg, bins, 0);
        zmin_kernel<<<NPAIRS * NB_, 256, 0, stream>>>(pred, seg_cnt, seg, bins,
                                                      partial_s, partial_c, 0);
    } else {
        for (int p = 0; p < NPAIRS; ++p) {
            reset_alloc_kernel<<<1, 1, 0, stream>>>(alloc);
            fill_kernel<<<BLKS_PER_PAIR, 256, 0, stream>>>(pred, xf, Km, alloc,
                                                           seg_cnt, seg, bins, p);
            zmin_kernel<<<NB_, 256, 0, stream>>>(pred, seg_cnt, seg, bins,
                                                 partial_s, partial_c, p);
        }
    }

    final_kernel<<<1, 256, 0, stream>>>(partial_s, partial_c, out);
}

// Round 12
// 175.132 us; speedup vs baseline: 1.5022x; 1.4231x over previous
//
#include <hip/hip_runtime.h>

#define H_ 768
#define W_ 1024
#define HW_ (H_ * W_)
#define NFRAMES 16
#define NPAIRS 15
#define NB_ 192                     // bands per pair, 4 rows each
#define BAND_ROWS 4
#define BAND_PX (BAND_ROWS * W_)    // 4096
#define ROWS_PER_BLK 4
#define BLKS_PER_PAIR (H_ / ROWS_PER_BLK)   // 192
#define MAXSEG 192                  // worst case: every row-block feeds a band
#define NBANDS_ALL (NPAIRS * NB_)   // 2880

// Composed per-pair transform: q = M*(d*[x_,y_,1]) + tq, with
// M = RB^T*RA, tq = RB^T*(tA-tB). x_=(u-cx)/fx, y_=(v-cy)/fy.
struct PairXf {
    float M[9];
    float tq[3];
};

__device__ __forceinline__ void quat_to_rot(const float* p, float R[9]) {
    float x = p[3], y = p[4], z = p[5], w = p[6];
    float n = sqrtf(x * x + y * y + z * z + w * w);
    x /= n; y /= n; z /= n; w /= n;
    R[0] = 1.f - 2.f * (y * y + z * z);
    R[1] = 2.f * (x * y - z * w);
    R[2] = 2.f * (x * z + y * w);
    R[3] = 2.f * (x * y + z * w);
    R[4] = 1.f - 2.f * (x * x + z * z);
    R[5] = 2.f * (y * z - x * w);
    R[6] = 2.f * (x * z - y * w);
    R[7] = 2.f * (y * z + x * w);
    R[8] = 1.f - 2.f * (x * x + y * y);
}

__global__ void prep_kernel(const float* __restrict__ pose,
                            PairXf* __restrict__ xfp,
                            unsigned* __restrict__ seg_cnt,
                            unsigned* __restrict__ alloc) {
    int t = threadIdx.x;
    if (t < NPAIRS) {
        float RA[9], RB[9];
        quat_to_rot(pose + t * 7, RA);
        quat_to_rot(pose + (t + 1) * 7, RB);
        PairXf X;
#pragma unroll
        for (int r = 0; r < 3; ++r)
#pragma unroll
            for (int c = 0; c < 3; ++c)
                X.M[r * 3 + c] = RB[0 + r] * RA[0 + c] + RB[3 + r] * RA[3 + c] + RB[6 + r] * RA[6 + c];
        float dx = pose[t * 7 + 0] - pose[(t + 1) * 7 + 0];
        float dy = pose[t * 7 + 1] - pose[(t + 1) * 7 + 1];
        float dz = pose[t * 7 + 2] - pose[(t + 1) * 7 + 2];
#pragma unroll
        for (int r = 0; r < 3; ++r)
            X.tq[r] = RB[0 + r] * dx + RB[3 + r] * dy + RB[6 + r] * dz;
        xfp[t] = X;
    }
    for (int i = t; i < NBANDS_ALL; i += 256) seg_cnt[i] = 0u;
    if (t == 0) alloc[0] = 0u;
}

__global__ void reset_alloc_kernel(unsigned* __restrict__ alloc) {
    alloc[0] = 0u;
}

// Single projection pass. Entry = (zq19<<12)|slot12, slot=((vi&3)<<10)|ui,
// zq=(float_bits(z)+0x1000)>>13 (monotone). Bands allocated from LDS
// counters with group-of-4 atomic aggregation (static indexing only).
__global__ void fill_kernel(const float* __restrict__ pred,
                            const PairXf* __restrict__ xfp,
                            const float* __restrict__ Km,
                            unsigned* __restrict__ alloc,
                            unsigned* __restrict__ seg_cnt,
                            uint2* __restrict__ seg,
                            unsigned* __restrict__ bins, int pair0) {
    int pair = pair0 + blockIdx.x / BLKS_PER_PAIR;
    int rowblk = blockIdx.x % BLKS_PER_PAIR;
    int t = threadIdx.x;
    int lane = t & 63, wid = t >> 6;
    __shared__ unsigned cnt[NB_];
    __shared__ unsigned basev[NB_];
    __shared__ unsigned wsum[4];
    __shared__ unsigned chunk_base;
    if (t < NB_) cnt[t] = 0u;
    __syncthreads();

    float fx = Km[0], cx = Km[2], fy = Km[4], cy = Km[5];
    float ifx = 1.f / fx, ify = 1.f / fy;
    PairXf X = xfp[pair];
    int row = rowblk * ROWS_PER_BLK + wid;
    int px0 = lane * 16;
    const float* src = pred + (size_t)pair * HW_ + row * W_ + px0;

    float y_ = ((float)row - cy) * ify;
    // hoist the y_/1 part of M*[x_,y_,1]
    float b0 = __fmaf_rn(X.M[1], y_, X.M[2]);
    float b1 = __fmaf_rn(X.M[4], y_, X.M[5]);
    float b2 = __fmaf_rn(X.M[7], y_, X.M[8]);

    unsigned entry[16];
    unsigned pk[16];

    // projection lambda: returns band (or ~0u) and entry value
    auto proj = [&](float d, int uoff, unsigned& band, unsigned& ev) {
        band = 0xFFFFFFFFu;
        if (d == 0.f) return;
        float x_ = ((float)(px0 + uoff) - cx) * ifx;
        float h0 = __fmaf_rn(X.M[0], x_, b0);
        float h1 = __fmaf_rn(X.M[3], x_, b1);
        float h2 = __fmaf_rn(X.M[6], x_, b2);
        float q0 = __fmaf_rn(d, h0, X.tq[0]);
        float q1 = __fmaf_rn(d, h1, X.tq[1]);
        float z  = __fmaf_rn(d, h2, X.tq[2]);
        if (!(z > 0.f)) return;
#if __has_builtin(__builtin_amdgcn_rcpf)
        float rz = __builtin_amdgcn_rcpf(z);
#else
        float rz = 1.0f / z;
#endif
        float u2 = __fmaf_rn(fx, q0 * rz, cx);
        float v2 = __fmaf_rn(fy, q1 * rz, cy);
        int ui = (int)rintf(u2);
        int vi = (int)rintf(v2);
        if (ui < 0 || ui >= W_ || vi < 0 || vi >= H_) return;
        unsigned zq = (__float_as_uint(z) + 0x1000u) >> 13;
        ev = (zq << 12) | (((unsigned)vi & 3u) << 10) | (unsigned)ui;
        band = (unsigned)(vi >> 2);
    };

#pragma unroll
    for (int k = 0; k < 4; ++k) {
        float4 d4 = *(const float4*)(src + 4 * k);
        unsigned g0, g1, g2, g3, e0, e1, e2, e3;
        proj(d4.x, 4 * k + 0, g0, e0);
        proj(d4.y, 4 * k + 1, g1, e1);
        proj(d4.z, 4 * k + 2, g2, e2);
        proj(d4.w, 4 * k + 3, g3, e3);
        entry[4 * k + 0] = e0; entry[4 * k + 1] = e1;
        entry[4 * k + 2] = e2; entry[4 * k + 3] = e3;
        if (g0 != 0xFFFFFFFFu && g0 == g1 && g1 == g2 && g2 == g3) {
            unsigned base = atomicAdd(&cnt[g0], 4u);      // common case: 1 atomic / 4 px
            pk[4 * k + 0] = (g0 << 16) | base;
            pk[4 * k + 1] = (g0 << 16) | (base + 1u);
            pk[4 * k + 2] = (g0 << 16) | (base + 2u);
            pk[4 * k + 3] = (g0 << 16) | (base + 3u);
        } else {
            pk[4 * k + 0] = (g0 != 0xFFFFFFFFu) ? ((g0 << 16) | atomicAdd(&cnt[g0], 1u)) : 0xFFFFFFFFu;
            pk[4 * k + 1] = (g1 != 0xFFFFFFFFu) ? ((g1 << 16) | atomicAdd(&cnt[g1], 1u)) : 0xFFFFFFFFu;
            pk[4 * k + 2] = (g2 != 0xFFFFFFFFu) ? ((g2 << 16) | atomicAdd(&cnt[g2], 1u)) : 0xFFFFFFFFu;
            pk[4 * k + 3] = (g3 != 0xFFFFFFFFu) ? ((g3 << 16) | atomicAdd(&cnt[g3], 1u)) : 0xFFFFFFFFu;
        }
    }
    __syncthreads();

    // parallel exclusive scan of cnt[0..191] (3 waves, shfl_up)
    unsigned cv = (t < NB_) ? cnt[t] : 0u;
    unsigned v = cv;
#pragma unroll
    for (int off = 1; off < 64; off <<= 1) {
        unsigned n = __shfl_up(v, off);
        if (lane >= off) v += n;
    }
    if (lane == 63) wsum[wid] = v;
    __syncthreads();
    if (t == 0) chunk_base = atomicAdd(alloc, wsum[0] + wsum[1] + wsum[2]);
    unsigned pref = ((wid >= 1) ? wsum[0] : 0u) + ((wid >= 2) ? wsum[1] : 0u);
    __syncthreads();
    if (t < NB_) {
        unsigned babs = chunk_base + pref + (v - cv);
        basev[t] = babs;
        if (cv) {
            unsigned gb = (unsigned)(pair * NB_ + t);
            unsigned si = atomicAdd(&seg_cnt[gb], 1u);
            seg[(size_t)gb * MAXSEG + si] = make_uint2(babs, cv);
        }
    }
    __syncthreads();
#pragma unroll
    for (int idx = 0; idx < 16; ++idx) {
        unsigned p = pk[idx];
        if (p != 0xFFFFFFFFu)
            bins[basev[p >> 16] + (p & 0xFFFFu)] = entry[idx];
    }
}

// Per-band LDS z-buffer (4x1024) + fused masked reduce -> partials.
__global__ void zmin_kernel(const float* __restrict__ pred,
                            const unsigned* __restrict__ seg_cnt,
                            const uint2* __restrict__ seg,
                            const unsigned* __restrict__ bins,
                            float* __restrict__ partial_s,
                            unsigned* __restrict__ partial_c, int pair0) {
    int gband = pair0 * NB_ + blockIdx.x;
    int pair = gband / NB_;
    int band = gband % NB_;
    int t = threadIdx.x;
    __shared__ unsigned zb[BAND_PX];
    __shared__ uint2 ssg[MAXSEG];
#pragma unroll
    for (int k = 0; k < BAND_PX / 256; ++k) zb[k * 256 + t] = 0xFFFFFFFFu;
    unsigned ns = seg_cnt[gband];
    if (t < ns) ssg[t] = seg[(size_t)gband * MAXSEG + t];
    __syncthreads();

    for (unsigned j = 0; j < ns; ++j) {
        uint2 sg = ssg[j];
        for (unsigned i = sg.x + t; i < sg.x + sg.y; i += 256) {
            unsigned e = bins[i];
            atomicMin(&zb[e & 4095u], e >> 12);
        }
    }
    __syncthreads();

    const float4* pb4 = (const float4*)(pred + (size_t)(pair + 1) * HW_ + (size_t)band * BAND_PX);
    const uint4* zb4 = (const uint4*)zb;
    float s = 0.f; unsigned c = 0u;
#pragma unroll
    for (int k = 0; k < BAND_PX / 1024; ++k) {
        int i4 = k * 256 + t;
        uint4 b = zb4[i4];
        float4 db = pb4[i4];
        if (b.x != 0xFFFFFFFFu) { s += __uint_as_float(b.x << 13) - db.x; ++c; } else if (db.x != 0.f) ++c;
        if (b.y != 0xFFFFFFFFu) { s += __uint_as_float(b.y << 13) - db.y; ++c; } else if (db.y != 0.f) ++c;
        if (b.z != 0xFFFFFFFFu) { s += __uint_as_float(b.z << 13) - db.z; ++c; } else if (db.z != 0.f) ++c;
        if (b.w != 0xFFFFFFFFu) { s += __uint_as_float(b.w << 13) - db.w; ++c; } else if (db.w != 0.f) ++c;
    }
    for (int off = 32; off > 0; off >>= 1) {
        s += __shfl_down(s, off);
        c += __shfl_down(c, off);
    }
    __shared__ float ls[4];
    __shared__ unsigned lc[4];
    int lane = t & 63, wid = t >> 6;
    if (lane == 0) { ls[wid] = s; lc[wid] = c; }
    __syncthreads();
    if (t == 0) {
        partial_s[gband] = ls[0] + ls[1] + ls[2] + ls[3];
        partial_c[gband] = lc[0] + lc[1] + lc[2] + lc[3];
    }
}

__global__ void final_kernel(const float* __restrict__ partial_s,
                             const unsigned* __restrict__ partial_c,
                             float* __restrict__ out) {
    int t = threadIdx.x;
    __shared__ float ps[NPAIRS];
    __shared__ unsigned pc[NPAIRS];
    int pair = t >> 4, sub = t & 15;
    float s = 0.f; unsigned c = 0u;
    if (t < NPAIRS * 16) {
#pragma unroll
        for (int j = 0; j < 12; ++j) {
            int g = pair * NB_ + sub + j * 16;
            s += partial_s[g];
            c += partial_c[g];
        }
        for (int m = 1; m < 16; m <<= 1) { s += __shfl_xor(s, m); c += __shfl_xor(c, m); }
        if (sub == 0) { ps[pair] = s; pc[pair] = c; }
    }
    __syncthreads();
    if (t == 0) {
        float acc = 0.f;
        for (int p = 0; p < NPAIRS; ++p) {
            unsigned cc = pc[p];
            if (cc < 1u) cc = 1u;
            acc += ps[p] / (float)cc;
        }
        out[0] = acc;
    }
}

extern "C" void kernel_launch(void* const* d_in, const int* in_sizes, int n_in,
                              void* d_out, int out_size, void* d_ws, size_t ws_size,
                              hipStream_t stream) {
    const float* pred = (const float*)d_in[0];   // (16,1,768,1024) f32
    const float* pose = (const float*)d_in[1];   // (16,7) f32
    const float* Km   = (const float*)d_in[2];   // (3,3) f32
    float* out = (float*)d_out;
    char* ws = (char*)d_ws;

    // ws layout (bytes):
    //       0: seg_cnt[2880]          (11520)
    //   11520: alloc[1]               (4)
    //   11524: partial_c[2880]        (11520)
    //   23044: partial_s[2880]        (11520) -> 34564
    //   34576: xfp[15] PairXf 48B     (720)   -> 35296
    //   35296: seg[2880*192] uint2    (4423680) -> 4458976
    // 4458976: bins (pathA: 15*HW*4 = 47185920 ; pathB: HW*4)
    unsigned* seg_cnt   = (unsigned*)ws;
    unsigned* alloc     = (unsigned*)(ws + 11520);
    unsigned* partial_c = (unsigned*)(ws + 11524);
    float*    partial_s = (float*)(ws + 23044);
    PairXf*   xfp       = (PairXf*)(ws + 34576);
    uint2*    seg       = (uint2*)(ws + 35296);
    unsigned* bins      = (unsigned*)(ws + 4458976);

    size_t needA = 4458976 + (size_t)NPAIRS * HW_ * sizeof(unsigned);
    bool pathA = ws_size >= needA;

    prep_kernel<<<1, 256, 0, stream>>>(pose, xfp, seg_cnt, alloc);

    if (pathA) {
        fill_kernel<<<NPAIRS * BLKS_PER_PAIR, 256, 0, stream>>>(pred, xfp, Km, alloc,
                                                                seg_cnt, seg, bins, 0);
        zmin_kernel<<<NPAIRS * NB_, 256, 0, stream>>>(pred, seg_cnt, seg, bins,
                                                      partial_s, partial_c, 0);
    } else {
        for (int p = 0; p < NPAIRS; ++p) {
            reset_alloc_kernel<<<1, 1, 0, stream>>>(alloc);
            fill_kernel<<<BLKS_PER_PAIR, 256, 0, stream>>>(pred, xfp, Km, alloc,
                                                           seg_cnt, seg, bins, p);
            zmin_kernel<<<NB_, 256, 0, stream>>>(pred, seg_cnt, seg, bins,
                                                 partial_s, partial_c, p);
        }
    }

    final_kernel<<<1, 256, 0, stream>>>(partial_s, partial_c, out);
}